// Round 4
// baseline (125.288 us; speedup 1.0000x reference)
//
#include <hip/hip_runtime.h>
#include <stdint.h>

#define IN_DIM 2048
#define OUT_DIM 2048
#define BATCH 4096
#define KDIM (2 * IN_DIM)   // 4096
#define KROWB (KDIM * 2)    // 8192 bytes per bf16 row
#define KH 2048             // K-half (split-K=2)
#define NTT 32              // K-tiles of 64 per half
#define BN_EPS 1e-5f

typedef __attribute__((ext_vector_type(8))) short bf16x8;
typedef __attribute__((ext_vector_type(4))) float f32x4;

__device__ __forceinline__ unsigned short f2bf(float f) {
  union { float f; unsigned u; } v; v.f = f;
  unsigned r = v.u + 0x7FFFu + ((v.u >> 16) & 1u);  // RNE
  return (unsigned short)(r >> 16);
}

// K1a: A = [wavelet(x) | x] bf16, row-major (BATCH x KDIM)
__global__ void prep_act(const float* __restrict__ x,
                         const float* __restrict__ scale,
                         const float* __restrict__ translate,
                         unsigned short* __restrict__ A) {
  int e = (blockIdx.x * 256 + threadIdx.x) * 4;
  int b = e / IN_DIM;
  int i = e % IN_DIM;
  float4 xv = *(const float4*)(x + e);
  float4 sv = *(const float4*)(scale + i);
  float4 tv = *(const float4*)(translate + i);
  const float c = 0.7511255444649425f;  // pi^-0.25
  float u0 = (xv.x - tv.x) / fmaxf(sv.x, 1e-3f);
  float u1 = (xv.y - tv.y) / fmaxf(sv.y, 1e-3f);
  float u2 = (xv.z - tv.z) / fmaxf(sv.z, 1e-3f);
  float u3 = (xv.w - tv.w) / fmaxf(sv.w, 1e-3f);
  ushort4 wv, xb;
  wv.x = f2bf(c * __cosf(3.0f * u0) * __expf(-0.5f * u0 * u0));
  wv.y = f2bf(c * __cosf(3.0f * u1) * __expf(-0.5f * u1 * u1));
  wv.z = f2bf(c * __cosf(3.0f * u2) * __expf(-0.5f * u2 * u2));
  wv.w = f2bf(c * __cosf(3.0f * u3) * __expf(-0.5f * u3 * u3));
  xb.x = f2bf(xv.x); xb.y = f2bf(xv.y); xb.z = f2bf(xv.z); xb.w = f2bf(xv.w);
  *(ushort4*)(A + (size_t)b * KDIM + i) = wv;
  *(ushort4*)(A + (size_t)b * KDIM + IN_DIM + i) = xb;
}

// K1b: W = [wave_weight | 0.3*base_weight] bf16, row-major (OUT_DIM x KDIM)
__global__ void prep_w(const float* __restrict__ ww,
                       const float* __restrict__ bw,
                       unsigned short* __restrict__ W) {
  int e = (blockIdx.x * 256 + threadIdx.x) * 4;
  int o = e / IN_DIM;
  int k = e % IN_DIM;
  float4 a = *(const float4*)(ww + e);
  float4 b = *(const float4*)(bw + e);
  ushort4 wa, wb;
  wa.x = f2bf(a.x); wa.y = f2bf(a.y); wa.z = f2bf(a.z); wa.w = f2bf(a.w);
  wb.x = f2bf(0.3f * b.x); wb.y = f2bf(0.3f * b.y);
  wb.z = f2bf(0.3f * b.z); wb.w = f2bf(0.3f * b.w);
  *(ushort4*)(W + (size_t)o * KDIM + k) = wa;
  *(ushort4*)(W + (size_t)o * KDIM + IN_DIM + k) = wb;
}

// ------- split-K 256x256 GEMM, 8 waves of 128x64, BK=64 -------
// LDS per parity (64K): A0=0 (rows 0-127), A1=16384 (rows 128-255),
// B0=32768, B1=49152. ALL 8 loads for tile u+1 issued at ph1 of tile u;
// single vmcnt(0) at ph4-end (loads are then 3 phases ~1800cyc old).
// Race-free by construction: each wave drains its own loads, then barrier.

#define GLDS(gp, lo) __builtin_amdgcn_global_load_lds( \
    (const __attribute__((address_space(1))) void*)(gp), \
    (__attribute__((address_space(3))) void*)(lds + (lo) + ldsl), 16, 0, 0)

#define STG(u_, gp_, t_) do { \
  GLDS((gp_) + (size_t)(t_) * 128, (u_)); \
  GLDS((gp_) + (size_t)64 * KROWB + (size_t)(t_) * 128, (u_) + 8192); \
} while (0)

#define LDA4(mh, ss) do { \
  af[0] = *(const bf16x8*)(lds + P + rA + ((mh) * 4 + 0) * 2048 + (ss)); \
  af[1] = *(const bf16x8*)(lds + P + rA + ((mh) * 4 + 1) * 2048 + (ss)); \
  af[2] = *(const bf16x8*)(lds + P + rA + ((mh) * 4 + 2) * 2048 + (ss)); \
  af[3] = *(const bf16x8*)(lds + P + rA + ((mh) * 4 + 3) * 2048 + (ss)); \
} while (0)

#define LDB4(dst, ss) do { \
  dst[0] = *(const bf16x8*)(lds + P + rB + 0 * 2048 + (ss)); \
  dst[1] = *(const bf16x8*)(lds + P + rB + 1 * 2048 + (ss)); \
  dst[2] = *(const bf16x8*)(lds + P + rB + 2 * 2048 + (ss)); \
  dst[3] = *(const bf16x8*)(lds + P + rB + 3 * 2048 + (ss)); \
} while (0)

#define MM16(mh, bfr) do { \
  __builtin_amdgcn_s_setprio(1); \
  _Pragma("unroll") for (int i2 = 0; i2 < 4; ++i2) \
  _Pragma("unroll") for (int j2 = 0; j2 < 4; ++j2) \
    acc[(mh) * 4 + i2][j2] = __builtin_amdgcn_mfma_f32_16x16x32_bf16( \
        af[i2], bfr[j2], acc[(mh) * 4 + i2][j2], 0, 0, 0); \
  __builtin_amdgcn_s_setprio(0); \
} while (0)

#define LGKM0() asm volatile("s_waitcnt lgkmcnt(0)" ::: "memory")
#define VMW0()  asm volatile("s_waitcnt vmcnt(0)" ::: "memory")
#define BAR()   do { asm volatile("" ::: "memory"); __builtin_amdgcn_s_barrier(); \
                     asm volatile("" ::: "memory"); } while (0)

#define KTILE(u, DOST) do { \
  const int P = ((u) & 1) << 16; \
  const int Q = P ^ 65536; \
  LDA4(0, s0); LDB4(b0, s0); \
  if (DOST) { STG(Q + 32768, bS0, (u) + 1); STG(Q + 49152, bS1, (u) + 1); \
              STG(Q + 0, aS0, (u) + 1); STG(Q + 16384, aS1, (u) + 1); } \
  BAR(); MM16(0, b0); LGKM0(); BAR(); \
  LDA4(1, s0); \
  BAR(); MM16(1, b0); LGKM0(); BAR(); \
  LDA4(0, s1); LDB4(b1, s1); \
  BAR(); MM16(0, b1); LGKM0(); BAR(); \
  LDA4(1, s1); \
  BAR(); MM16(1, b1); LGKM0(); if (DOST) VMW0(); BAR(); \
} while (0)

__global__ __launch_bounds__(512, 2) void gemm256(
    const unsigned short* __restrict__ A,
    const unsigned short* __restrict__ W,
    float* __restrict__ P0, float* __restrict__ P1) {
  __shared__ char lds[131072];
  const int tid = threadIdx.x;
  const int lane = tid & 63;
  const int wave = tid >> 6;
  const int wm = wave >> 2;   // 0..1 -> 128-row M half
  const int wn = wave & 3;    // 0..3 -> 64-col N quarter

  // XCD-aware bijective swizzle (256 blocks, %8==0); sw = [kz:1][m:4][n:3]
  const int sw = ((blockIdx.x & 7) << 5) | (blockIdx.x >> 3);
  const int kz = sw >> 7;
  const int brow = ((sw >> 3) & 15) * 256;
  const int bcol = (sw & 7) * 256;
  const size_t kb = (size_t)kz * (KH * 2);  // byte offset of K-half

  // staging: thread -> row tid>>3 (0..63), pre-swizzled 16B slot
  const int srow = tid >> 3;
  const int gc16 = (tid & 7) ^ (srow & 7);
  const char* aS0 = (const char*)A + (size_t)(brow + srow) * KROWB + kb + gc16 * 16;
  const char* aS1 = aS0 + (size_t)128 * KROWB;
  const char* bS0 = (const char*)W + (size_t)(bcol + srow) * KROWB + kb + gc16 * 16;
  const char* bS1 = bS0 + (size_t)128 * KROWB;
  const int ldsl = wave * 1024;  // + lane*16 implicit in global_load_lds

  // fragment read offsets (swizzled): byte = row*128 + ((c16 ^ (row&7))<<4)
  const int rA = (wm * 128 + (lane & 15)) * 128;
  const int rB = 32768 + (wn * 64 + (lane & 15)) * 128;
  const int s0 = (((lane >> 4)    ) ^ (lane & 7)) << 4;  // k 0-31
  const int s1 = ((4 + (lane >> 4)) ^ (lane & 7)) << 4;  // k 32-63

  f32x4 acc[8][4];
#pragma unroll
  for (int m = 0; m < 8; ++m)
#pragma unroll
    for (int n = 0; n < 4; ++n)
      acc[m][n] = (f32x4){0.f, 0.f, 0.f, 0.f};
  bf16x8 af[4], b0[4], b1[4];

  // prologue: stage tile 0 fully, drain, publish
  STG(32768, bS0, 0); STG(49152, bS1, 0); STG(0, aS0, 0); STG(16384, aS1, 0);
  VMW0(); BAR();

  for (int u = 0; u < NTT - 1; ++u)
    KTILE(u, 1);
  KTILE(NTT - 1, 0);

  float* Pz = kz ? P1 : P0;
  const int r0 = brow + wm * 128 + (lane >> 4) * 4;
  const int c0 = bcol + wn * 64 + (lane & 15);
#pragma unroll
  for (int m = 0; m < 8; ++m)
#pragma unroll
    for (int n = 0; n < 4; ++n)
#pragma unroll
      for (int j = 0; j < 4; ++j)
        Pz[(size_t)(r0 + m * 16 + j) * OUT_DIM + (c0 + n * 16)] = acc[m][n][j];
}

// K3a: per-column stats over P0+P1 (read-only; no Y materialization)
__global__ void colstats2(const float* __restrict__ P0,
                          const float* __restrict__ P1,
                          float* __restrict__ sums, float* __restrict__ sqs) {
  int col = (blockIdx.x & 7) * 256 + threadIdx.x;
  int r0 = (blockIdx.x >> 3) * 128;
  float s = 0.f, q = 0.f;
  for (int r = 0; r < 128; ++r) {
    size_t idx = (size_t)(r0 + r) * OUT_DIM + col;
    float v = P0[idx] + P1[idx];
    s += v;
    q += v * v;
  }
  atomicAdd(&sums[col], s);
  atomicAdd(&sqs[col], q);
}

// K3b: fused partial-add + batchnorm, Y (=P0=d_out) in-place
__global__ void bnorm2(const float* __restrict__ P1, float* __restrict__ Y,
                       const float* __restrict__ sums, const float* __restrict__ sqs,
                       const float* __restrict__ gamma, const float* __restrict__ beta) {
  int e = (blockIdx.x * 256 + threadIdx.x) * 4;
  int c = e % OUT_DIM;
  float4 y = *(float4*)(Y + e);
  float4 p = *(const float4*)(P1 + e);
  y.x += p.x; y.y += p.y; y.z += p.z; y.w += p.w;
  float4 s = *(const float4*)(sums + c);
  float4 q = *(const float4*)(sqs + c);
  float4 g = *(const float4*)(gamma + c);
  float4 bb = *(const float4*)(beta + c);
  const float invB = 1.0f / (float)BATCH;
  float m0 = s.x * invB, m1 = s.y * invB, m2 = s.z * invB, m3 = s.w * invB;
  float i0 = rsqrtf(q.x * invB - m0 * m0 + BN_EPS);
  float i1 = rsqrtf(q.y * invB - m1 * m1 + BN_EPS);
  float i2 = rsqrtf(q.z * invB - m2 * m2 + BN_EPS);
  float i3 = rsqrtf(q.w * invB - m3 * m3 + BN_EPS);
  y.x = g.x * (y.x - m0) * i0 + bb.x;
  y.y = g.y * (y.y - m1) * i1 + bb.y;
  y.z = g.z * (y.z - m2) * i2 + bb.z;
  y.w = g.w * (y.w - m3) * i3 + bb.w;
  *(float4*)(Y + e) = y;
}

extern "C" void kernel_launch(void* const* d_in, const int* in_sizes, int n_in,
                              void* d_out, int out_size, void* d_ws, size_t ws_size,
                              hipStream_t stream) {
  const float* x         = (const float*)d_in[0];
  const float* scale     = (const float*)d_in[1];
  const float* translate = (const float*)d_in[2];
  const float* ww        = (const float*)d_in[3];
  const float* bw        = (const float*)d_in[4];
  const float* gamma     = (const float*)d_in[5];
  const float* beta      = (const float*)d_in[6];
  float* out = (float*)d_out;

  char* ws = (char*)d_ws;
  unsigned short* A = (unsigned short*)ws;                 // 33,554,432 B
  unsigned short* W = (unsigned short*)(ws + 33554432);    // 16,777,216 B
  float* P1   = (float*)(ws + 50331648);                   // 33,554,432 B
  float* sums = (float*)(ws + 83886080);
  float* sqs  = sums + OUT_DIM;

  hipMemsetAsync(sums, 0, 2 * OUT_DIM * sizeof(float), stream);
  prep_act<<<(BATCH * IN_DIM) / 1024, 256, 0, stream>>>(x, scale, translate, A);
  prep_w<<<(OUT_DIM * IN_DIM) / 1024, 256, 0, stream>>>(ww, bw, W);
  gemm256<<<256, 512, 0, stream>>>(A, W, out, P1);
  colstats2<<<256, 256, 0, stream>>>(out, P1, sums, sqs);
  bnorm2<<<(BATCH * OUT_DIM) / 1024, 256, 0, stream>>>(P1, out, sums, sqs, gamma, beta);
}

// Round 5
// 120.336 us; speedup vs baseline: 1.0412x; 1.0412x over previous
//
#include <hip/hip_runtime.h>
#include <stdint.h>

#define IN_DIM 2048
#define OUT_DIM 2048
#define BATCH 4096
#define KDIM (2 * IN_DIM)   // 4096
#define KROWB (KDIM * 2)    // 8192 bytes per bf16 row
#define KH 2048             // K-half (split-K=2)
#define NTT 64              // K-tiles of 32 per half
#define BN_EPS 1e-5f

typedef __attribute__((ext_vector_type(8))) short bf16x8;
typedef __attribute__((ext_vector_type(4))) float f32x4;

__device__ __forceinline__ unsigned short f2bf(float f) {
  union { float f; unsigned u; } v; v.f = f;
  unsigned r = v.u + 0x7FFFu + ((v.u >> 16) & 1u);  // RNE
  return (unsigned short)(r >> 16);
}

// K1a: A = [wavelet(x) | x] bf16, row-major (BATCH x KDIM)
__global__ void prep_act(const float* __restrict__ x,
                         const float* __restrict__ scale,
                         const float* __restrict__ translate,
                         unsigned short* __restrict__ A) {
  int e = (blockIdx.x * 256 + threadIdx.x) * 4;
  int b = e / IN_DIM;
  int i = e % IN_DIM;
  float4 xv = *(const float4*)(x + e);
  float4 sv = *(const float4*)(scale + i);
  float4 tv = *(const float4*)(translate + i);
  const float c = 0.7511255444649425f;  // pi^-0.25
  float u0 = (xv.x - tv.x) / fmaxf(sv.x, 1e-3f);
  float u1 = (xv.y - tv.y) / fmaxf(sv.y, 1e-3f);
  float u2 = (xv.z - tv.z) / fmaxf(sv.z, 1e-3f);
  float u3 = (xv.w - tv.w) / fmaxf(sv.w, 1e-3f);
  ushort4 wv, xb;
  wv.x = f2bf(c * __cosf(3.0f * u0) * __expf(-0.5f * u0 * u0));
  wv.y = f2bf(c * __cosf(3.0f * u1) * __expf(-0.5f * u1 * u1));
  wv.z = f2bf(c * __cosf(3.0f * u2) * __expf(-0.5f * u2 * u2));
  wv.w = f2bf(c * __cosf(3.0f * u3) * __expf(-0.5f * u3 * u3));
  xb.x = f2bf(xv.x); xb.y = f2bf(xv.y); xb.z = f2bf(xv.z); xb.w = f2bf(xv.w);
  *(ushort4*)(A + (size_t)b * KDIM + i) = wv;
  *(ushort4*)(A + (size_t)b * KDIM + IN_DIM + i) = xb;
}

// K1b: W = [wave_weight | 0.3*base_weight] bf16, row-major (OUT_DIM x KDIM)
__global__ void prep_w(const float* __restrict__ ww,
                       const float* __restrict__ bw,
                       unsigned short* __restrict__ W) {
  int e = (blockIdx.x * 256 + threadIdx.x) * 4;
  int o = e / IN_DIM;
  int k = e % IN_DIM;
  float4 a = *(const float4*)(ww + e);
  float4 b = *(const float4*)(bw + e);
  ushort4 wa, wb;
  wa.x = f2bf(a.x); wa.y = f2bf(a.y); wa.z = f2bf(a.z); wa.w = f2bf(a.w);
  wb.x = f2bf(0.3f * b.x); wb.y = f2bf(0.3f * b.y);
  wb.z = f2bf(0.3f * b.z); wb.w = f2bf(0.3f * b.w);
  *(ushort4*)(W + (size_t)o * KDIM + k) = wa;
  *(ushort4*)(W + (size_t)o * KDIM + IN_DIM + k) = wb;
}

// ---- split-K 256x256 GEMM, BK=32, 4-slot LDS ring (4 x 32KB = 128KB) ----
// Slot layout (32KB): A0=0, A1=8192, B0=16384, B1=24576 (each 128 rows x 32k).
// Unit storage: paired rows, lds_row lr = row>>1 (128B lines), within-line:
//   byte = lr*128 + (row&1)*64 + ((kslot ^ (lr&3))<<4)   [XOR swizzle]
// Stage for tile t+3 issued during tile t (writes slot (t+3)&3, reads (t)&3:
// disjoint). FIFO: after each tile-end vmcnt(8), last 2 tiles' stages (8
// loads) in flight; drained loads are 5-6 phases old -> no stall.

#define GLDS(gp, lo) __builtin_amdgcn_global_load_lds( \
    (const __attribute__((address_space(1))) void*)(gp), \
    (__attribute__((address_space(3))) void*)(lds + (lo) + ldsl), 16, 0, 0)

#define MM16(mh, bfr) do { \
  __builtin_amdgcn_s_setprio(1); \
  _Pragma("unroll") for (int i2 = 0; i2 < 4; ++i2) \
  _Pragma("unroll") for (int j2 = 0; j2 < 4; ++j2) \
    acc[(mh) * 4 + i2][j2] = __builtin_amdgcn_mfma_f32_16x16x32_bf16( \
        af[i2], bfr[j2], acc[(mh) * 4 + i2][j2], 0, 0, 0); \
  __builtin_amdgcn_s_setprio(0); \
} while (0)

#define LGKM0() asm volatile("s_waitcnt lgkmcnt(0)" ::: "memory")
#define VMW8()  asm volatile("s_waitcnt vmcnt(8)" ::: "memory")
#define VMW4()  asm volatile("s_waitcnt vmcnt(4)" ::: "memory")
#define VMW0()  asm volatile("s_waitcnt vmcnt(0)" ::: "memory")
#define NOW()   do { } while (0)
#define BAR()   do { asm volatile("" ::: "memory"); __builtin_amdgcn_s_barrier(); \
                     asm volatile("" ::: "memory"); } while (0)

// RS = read slot (0..3), SS = stage slot, SOFS = byte offset into a0p..b1p
#define KT(RS, SS, SOFS, DOST, TAILW) do { \
  const char* Au = lds + ((RS) << 15) + wmOff; \
  const char* Bu = lds + ((RS) << 15) + bnOff; \
  af[0] = *(const bf16x8*)(Au + 0 * 1024 + roff); \
  af[1] = *(const bf16x8*)(Au + 1 * 1024 + roff); \
  af[2] = *(const bf16x8*)(Au + 2 * 1024 + roff); \
  af[3] = *(const bf16x8*)(Au + 3 * 1024 + roff); \
  bfr[0] = *(const bf16x8*)(Bu + 0 * 1024 + roff); \
  bfr[1] = *(const bf16x8*)(Bu + 1 * 1024 + roff); \
  bfr[2] = *(const bf16x8*)(Bu + 2 * 1024 + roff); \
  bfr[3] = *(const bf16x8*)(Bu + 3 * 1024 + roff); \
  if (DOST) { GLDS(a0p + (SOFS), ((SS) << 15) + 0); \
              GLDS(a1p + (SOFS), ((SS) << 15) + 8192); } \
  BAR(); MM16(0, bfr); LGKM0(); BAR(); \
  af[0] = *(const bf16x8*)(Au + 4 * 1024 + roff); \
  af[1] = *(const bf16x8*)(Au + 5 * 1024 + roff); \
  af[2] = *(const bf16x8*)(Au + 6 * 1024 + roff); \
  af[3] = *(const bf16x8*)(Au + 7 * 1024 + roff); \
  if (DOST) { GLDS(b0p + (SOFS), ((SS) << 15) + 16384); \
              GLDS(b1p + (SOFS), ((SS) << 15) + 24576); } \
  BAR(); MM16(1, bfr); LGKM0(); TAILW; BAR(); \
} while (0)

__global__ __launch_bounds__(512, 2) void gemm256(
    const unsigned short* __restrict__ A,
    const unsigned short* __restrict__ W,
    float* __restrict__ P0, float* __restrict__ P1) {
  __shared__ char lds[131072];
  const int tid = threadIdx.x;
  const int lane = tid & 63;
  const int wave = tid >> 6;
  const int wm = wave >> 2;   // 0..1 -> 128-row M half
  const int wn = wave & 3;    // 0..3 -> 64-col N quarter

  // XCD-aware bijective swizzle (256 blocks, %8==0); sw = [kz:1][m:4][n:3]
  const int sw = ((blockIdx.x & 7) << 5) | (blockIdx.x >> 3);
  const int kz = sw >> 7;
  const int brow = ((sw >> 3) & 15) * 256;
  const int bcol = (sw & 7) * 256;
  const size_t kb = (size_t)kz * (KH * 2);  // byte offset of K-half

  // staging: thread tid writes LDS unit byte tid*16 = (lr=tid>>3, half=(tid>>2)&1,
  // pos=tid&3); that slot holds global (row = 2*lr+half, kslot = pos ^ (lr&3)).
  const int slr = tid >> 3;
  const int srow2 = 2 * slr + ((tid >> 2) & 1);
  const int skslot = (tid & 3) ^ (slr & 3);
  const char* aS0 = (const char*)A + (size_t)(brow + srow2) * KROWB + kb + skslot * 16;
  const char* aS1 = aS0 + (size_t)128 * KROWB;
  const char* bS0 = (const char*)W + (size_t)(bcol + srow2) * KROWB + kb + skslot * 16;
  const char* bS1 = bS0 + (size_t)128 * KROWB;
  const int ldsl = wave * 1024;  // + lane*16 implicit in global_load_lds

  // fragment read: row = f*16 + (lane&15), k = (lane>>4)*8 .. +8
  // byte(f) = f*1024 + roff,  roff = lh*128 + par*64 + ((p ^ (lh&3))<<4)
  const int lh = (lane & 15) >> 1;
  const int roff = lh * 128 + (lane & 1) * 64 + (((lane >> 4) ^ (lh & 3)) << 4);
  const int wmOff = wm * 8192;
  const int bnOff = 16384 + (wn >> 1) * 8192 + (wn & 1) * 4096;

  f32x4 acc[8][4];
#pragma unroll
  for (int m = 0; m < 8; ++m)
#pragma unroll
    for (int n = 0; n < 4; ++n)
      acc[m][n] = (f32x4){0.f, 0.f, 0.f, 0.f};
  bf16x8 af[4], bfr[4];

  // prologue: stage tiles 0,1,2 (12 loads); drain to 8 -> tile 0 landed.
  GLDS(aS0, 0); GLDS(aS1, 8192); GLDS(bS0, 16384); GLDS(bS1, 24576);
  GLDS(aS0 + 64, 32768); GLDS(aS1 + 64, 32768 + 8192);
  GLDS(bS0 + 64, 32768 + 16384); GLDS(bS1 + 64, 32768 + 24576);
  GLDS(aS0 + 128, 65536); GLDS(aS1 + 128, 65536 + 8192);
  GLDS(bS0 + 128, 65536 + 16384); GLDS(bS1 + 128, 65536 + 24576);
  VMW8(); BAR();

  // stage pointers for tile t+3 (t = loop tile index)
  const char* a0p = aS0 + 192;
  const char* a1p = aS1 + 192;
  const char* b0p = bS0 + 192;
  const char* b1p = bS1 + 192;

  for (int tt = 0; tt < 60; tt += 4) {  // tiles 0..59, all staging
    KT(0, 3, 0,   1, VMW8());
    KT(1, 0, 64,  1, VMW8());
    KT(2, 1, 128, 1, VMW8());
    KT(3, 2, 192, 1, VMW8());
    a0p += 256; a1p += 256; b0p += 256; b1p += 256;
  }
  // t=60 stages tile 63 (a0p now = aS0 + 63*64); tail drains
  KT(0, 3, 0, 1, VMW8());
  KT(1, 0, 0, 0, VMW4());
  KT(2, 0, 0, 0, VMW0());
  KT(3, 0, 0, 0, NOW());

  float* Pz = kz ? P1 : P0;
  const int r0 = brow + wm * 128 + (lane >> 4) * 4;
  const int c0 = bcol + wn * 64 + (lane & 15);
#pragma unroll
  for (int m = 0; m < 8; ++m)
#pragma unroll
    for (int n = 0; n < 4; ++n)
#pragma unroll
      for (int j = 0; j < 4; ++j)
        Pz[(size_t)(r0 + m * 16 + j) * OUT_DIM + (c0 + n * 16)] = acc[m][n][j];
}

// K3a: per-column stats over P0+P1 (read-only)
__global__ void colstats2(const float* __restrict__ P0,
                          const float* __restrict__ P1,
                          float* __restrict__ sums, float* __restrict__ sqs) {
  int col = (blockIdx.x & 7) * 256 + threadIdx.x;
  int r0 = (blockIdx.x >> 3) * 128;
  float s = 0.f, q = 0.f;
  for (int r = 0; r < 128; ++r) {
    size_t idx = (size_t)(r0 + r) * OUT_DIM + col;
    float v = P0[idx] + P1[idx];
    s += v;
    q += v * v;
  }
  atomicAdd(&sums[col], s);
  atomicAdd(&sqs[col], q);
}

// K3b: fused partial-add + batchnorm, Y (=P0=d_out) in-place
__global__ void bnorm2(const float* __restrict__ P1, float* __restrict__ Y,
                       const float* __restrict__ sums, const float* __restrict__ sqs,
                       const float* __restrict__ gamma, const float* __restrict__ beta) {
  int e = (blockIdx.x * 256 + threadIdx.x) * 4;
  int c = e % OUT_DIM;
  float4 y = *(float4*)(Y + e);
  float4 p = *(const float4*)(P1 + e);
  y.x += p.x; y.y += p.y; y.z += p.z; y.w += p.w;
  float4 s = *(const float4*)(sums + c);
  float4 q = *(const float4*)(sqs + c);
  float4 g = *(const float4*)(gamma + c);
  float4 bb = *(const float4*)(beta + c);
  const float invB = 1.0f / (float)BATCH;
  float m0 = s.x * invB, m1 = s.y * invB, m2 = s.z * invB, m3 = s.w * invB;
  float i0 = rsqrtf(q.x * invB - m0 * m0 + BN_EPS);
  float i1 = rsqrtf(q.y * invB - m1 * m1 + BN_EPS);
  float i2 = rsqrtf(q.z * invB - m2 * m2 + BN_EPS);
  float i3 = rsqrtf(q.w * invB - m3 * m3 + BN_EPS);
  y.x = g.x * (y.x - m0) * i0 + bb.x;
  y.y = g.y * (y.y - m1) * i1 + bb.y;
  y.z = g.z * (y.z - m2) * i2 + bb.z;
  y.w = g.w * (y.w - m3) * i3 + bb.w;
  *(float4*)(Y + e) = y;
}

extern "C" void kernel_launch(void* const* d_in, const int* in_sizes, int n_in,
                              void* d_out, int out_size, void* d_ws, size_t ws_size,
                              hipStream_t stream) {
  const float* x         = (const float*)d_in[0];
  const float* scale     = (const float*)d_in[1];
  const float* translate = (const float*)d_in[2];
  const float* ww        = (const float*)d_in[3];
  const float* bw        = (const float*)d_in[4];
  const float* gamma     = (const float*)d_in[5];
  const float* beta      = (const float*)d_in[6];
  float* out = (float*)d_out;

  char* ws = (char*)d_ws;
  unsigned short* A = (unsigned short*)ws;                 // 33,554,432 B
  unsigned short* W = (unsigned short*)(ws + 33554432);    // 16,777,216 B
  float* P1   = (float*)(ws + 50331648);                   // 33,554,432 B
  float* sums = (float*)(ws + 83886080);
  float* sqs  = sums + OUT_DIM;

  hipMemsetAsync(sums, 0, 2 * OUT_DIM * sizeof(float), stream);
  prep_act<<<(BATCH * IN_DIM) / 1024, 256, 0, stream>>>(x, scale, translate, A);
  prep_w<<<(OUT_DIM * IN_DIM) / 1024, 256, 0, stream>>>(ww, bw, W);
  gemm256<<<256, 512, 0, stream>>>(A, W, out, P1);
  colstats2<<<256, 256, 0, stream>>>(out, P1, sums, sqs);
  bnorm2<<<(BATCH * OUT_DIM) / 1024, 256, 0, stream>>>(P1, out, sums, sqs, gamma, beta);
}

// Round 6
// 109.176 us; speedup vs baseline: 1.1476x; 1.1022x over previous
//
#include <hip/hip_runtime.h>
#include <stdint.h>

#define IN_DIM 2048
#define OUT_DIM 2048
#define BATCH 4096
#define KDIM (2 * IN_DIM)   // 4096
#define KROWB (KDIM * 2)    // 8192 bytes per bf16 row
#define KH 2048             // K-half (split-K=2)
#define BN_EPS 1e-5f

typedef __attribute__((ext_vector_type(8))) short bf16x8;
typedef __attribute__((ext_vector_type(4))) float f32x4;

__device__ __forceinline__ unsigned short f2bf(float f) {
  union { float f; unsigned u; } v; v.f = f;
  unsigned r = v.u + 0x7FFFu + ((v.u >> 16) & 1u);  // RNE
  return (unsigned short)(r >> 16);
}

// K1a: A = [wavelet(x) | x] bf16, row-major (BATCH x KDIM)
__global__ void prep_act(const float* __restrict__ x,
                         const float* __restrict__ scale,
                         const float* __restrict__ translate,
                         unsigned short* __restrict__ A) {
  int e = (blockIdx.x * 256 + threadIdx.x) * 4;
  int b = e / IN_DIM;
  int i = e % IN_DIM;
  float4 xv = *(const float4*)(x + e);
  float4 sv = *(const float4*)(scale + i);
  float4 tv = *(const float4*)(translate + i);
  const float c = 0.7511255444649425f;  // pi^-0.25
  float u0 = (xv.x - tv.x) / fmaxf(sv.x, 1e-3f);
  float u1 = (xv.y - tv.y) / fmaxf(sv.y, 1e-3f);
  float u2 = (xv.z - tv.z) / fmaxf(sv.z, 1e-3f);
  float u3 = (xv.w - tv.w) / fmaxf(sv.w, 1e-3f);
  ushort4 wv, xb;
  wv.x = f2bf(c * __cosf(3.0f * u0) * __expf(-0.5f * u0 * u0));
  wv.y = f2bf(c * __cosf(3.0f * u1) * __expf(-0.5f * u1 * u1));
  wv.z = f2bf(c * __cosf(3.0f * u2) * __expf(-0.5f * u2 * u2));
  wv.w = f2bf(c * __cosf(3.0f * u3) * __expf(-0.5f * u3 * u3));
  xb.x = f2bf(xv.x); xb.y = f2bf(xv.y); xb.z = f2bf(xv.z); xb.w = f2bf(xv.w);
  *(ushort4*)(A + (size_t)b * KDIM + i) = wv;
  *(ushort4*)(A + (size_t)b * KDIM + IN_DIM + i) = xb;
}

// K1b: W = [wave_weight | 0.3*base_weight] bf16, row-major (OUT_DIM x KDIM)
__global__ void prep_w(const float* __restrict__ ww,
                       const float* __restrict__ bw,
                       unsigned short* __restrict__ W) {
  int e = (blockIdx.x * 256 + threadIdx.x) * 4;
  int o = e / IN_DIM;
  int k = e % IN_DIM;
  float4 a = *(const float4*)(ww + e);
  float4 b = *(const float4*)(bw + e);
  ushort4 wa, wb;
  wa.x = f2bf(a.x); wa.y = f2bf(a.y); wa.z = f2bf(a.z); wa.w = f2bf(a.w);
  wb.x = f2bf(0.3f * b.x); wb.y = f2bf(0.3f * b.y);
  wb.z = f2bf(0.3f * b.z); wb.w = f2bf(0.3f * b.w);
  *(ushort4*)(W + (size_t)o * KDIM + k) = wa;
  *(ushort4*)(W + (size_t)o * KDIM + IN_DIM + k) = wb;
}

// ---- split-K 256x256 GEMM, BK=32, 4-slot LDS ring, ONE barrier per tile ----
// Slot (32KB): A0=0, A1=8192, B0=16384, B1=24576. Paired-row storage:
//   byte = lr*128 + (row&1)*64 + ((kslot ^ (lr&3))<<4)   [XOR swizzle]
// Tile t: reads slot t&3, stages tile t+3 into slot (t+3)&3 (= slot of t-1;
// safe: lgkmcnt(0) precedes each tile-end barrier, so no in-flight ds_reads
// when the next tile's GLDS lands there). FIFO: VMW8 at tile end drains the
// stage issued 3 tiles ago (for t+1); barrier publishes it across waves.

#define GLDS(gp, lo) __builtin_amdgcn_global_load_lds( \
    (const __attribute__((address_space(1))) void*)(gp), \
    (__attribute__((address_space(3))) void*)(lds + (lo) + ldsl), 16, 0, 0)

#define MM16(mh) do { \
  __builtin_amdgcn_s_setprio(1); \
  _Pragma("unroll") for (int i2 = 0; i2 < 4; ++i2) \
  _Pragma("unroll") for (int j2 = 0; j2 < 4; ++j2) \
    acc[(mh) * 4 + i2][j2] = __builtin_amdgcn_mfma_f32_16x16x32_bf16( \
        af[i2], bfr[j2], acc[(mh) * 4 + i2][j2], 0, 0, 0); \
  __builtin_amdgcn_s_setprio(0); \
} while (0)

#define LGKM0() asm volatile("s_waitcnt lgkmcnt(0)" ::: "memory")
#define VMW8()  asm volatile("s_waitcnt vmcnt(8)" ::: "memory")
#define VMW4()  asm volatile("s_waitcnt vmcnt(4)" ::: "memory")
#define VMW0()  asm volatile("s_waitcnt vmcnt(0)" ::: "memory")
#define NOW()   do { } while (0)
#define BAR()   do { asm volatile("" ::: "memory"); __builtin_amdgcn_s_barrier(); \
                     asm volatile("" ::: "memory"); } while (0)

// RS = read slot, SS = stage slot, SOFS = byte offset into stage pointers
#define KT(RS, SS, SOFS, DOST, TAILW) do { \
  const char* Au = lds + ((RS) << 15) + wmOff; \
  const char* Bu = lds + ((RS) << 15) + bnOff; \
  af[0] = *(const bf16x8*)(Au + 0 * 1024 + roff); \
  af[1] = *(const bf16x8*)(Au + 1 * 1024 + roff); \
  af[2] = *(const bf16x8*)(Au + 2 * 1024 + roff); \
  af[3] = *(const bf16x8*)(Au + 3 * 1024 + roff); \
  bfr[0] = *(const bf16x8*)(Bu + 0 * 1024 + roff); \
  bfr[1] = *(const bf16x8*)(Bu + 1 * 1024 + roff); \
  bfr[2] = *(const bf16x8*)(Bu + 2 * 1024 + roff); \
  bfr[3] = *(const bf16x8*)(Bu + 3 * 1024 + roff); \
  if (DOST) { GLDS(a0p + (SOFS), ((SS) << 15) + 0); \
              GLDS(a1p + (SOFS), ((SS) << 15) + 8192); \
              GLDS(b0p + (SOFS), ((SS) << 15) + 16384); \
              GLDS(b1p + (SOFS), ((SS) << 15) + 24576); } \
  MM16(0); \
  af[0] = *(const bf16x8*)(Au + 4 * 1024 + roff); \
  af[1] = *(const bf16x8*)(Au + 5 * 1024 + roff); \
  af[2] = *(const bf16x8*)(Au + 6 * 1024 + roff); \
  af[3] = *(const bf16x8*)(Au + 7 * 1024 + roff); \
  MM16(1); \
  LGKM0(); TAILW; BAR(); \
} while (0)

__global__ __launch_bounds__(512, 2) void gemm256(
    const unsigned short* __restrict__ A,
    const unsigned short* __restrict__ W,
    float* __restrict__ P0, float* __restrict__ P1,
    float* __restrict__ sums, float* __restrict__ sqs) {
  __shared__ char lds[131072];
  const int tid = threadIdx.x;
  const int lane = tid & 63;
  const int wave = tid >> 6;
  const int wm = wave >> 2;   // 0..1 -> 128-row M half
  const int wn = wave & 3;    // 0..3 -> 64-col N quarter

  // XCD-aware bijective swizzle (256 blocks, %8==0); sw = [kz:1][m:4][n:3]
  const int sw = ((blockIdx.x & 7) << 5) | (blockIdx.x >> 3);
  const int kz = sw >> 7;
  const int brow = ((sw >> 3) & 15) * 256;
  const int bcol = (sw & 7) * 256;
  const size_t kb = (size_t)kz * (KH * 2);  // byte offset of K-half

  // staging: thread tid writes LDS unit byte tid*16 = (lr=tid>>3, half,
  // pos=tid&3); that slot holds global (row = 2*lr+half, kslot = pos^(lr&3)).
  const int slr = tid >> 3;
  const int srow2 = 2 * slr + ((tid >> 2) & 1);
  const int skslot = (tid & 3) ^ (slr & 3);
  const char* aS0 = (const char*)A + (size_t)(brow + srow2) * KROWB + kb + skslot * 16;
  const char* aS1 = aS0 + (size_t)128 * KROWB;
  const char* bS0 = (const char*)W + (size_t)(bcol + srow2) * KROWB + kb + skslot * 16;
  const char* bS1 = bS0 + (size_t)128 * KROWB;
  const int ldsl = wave * 1024;  // + lane*16 implicit in global_load_lds

  // fragment read: row = f*16 + (lane&15), k = (lane>>4)*8 .. +8
  const int lh = (lane & 15) >> 1;
  const int roff = lh * 128 + (lane & 1) * 64 + (((lane >> 4) ^ (lh & 3)) << 4);
  const int wmOff = wm * 8192;
  const int bnOff = 16384 + (wn >> 1) * 8192 + (wn & 1) * 4096;

  f32x4 acc[8][4];
#pragma unroll
  for (int m = 0; m < 8; ++m)
#pragma unroll
    for (int n = 0; n < 4; ++n)
      acc[m][n] = (f32x4){0.f, 0.f, 0.f, 0.f};
  bf16x8 af[4], bfr[4];

  // prologue: stage tiles 0,1,2 (12 loads); drain to 8 -> tile 0 landed.
  GLDS(aS0, 0); GLDS(aS1, 8192); GLDS(bS0, 16384); GLDS(bS1, 24576);
  GLDS(aS0 + 64, 32768); GLDS(aS1 + 64, 32768 + 8192);
  GLDS(bS0 + 64, 32768 + 16384); GLDS(bS1 + 64, 32768 + 24576);
  GLDS(aS0 + 128, 65536); GLDS(aS1 + 128, 65536 + 8192);
  GLDS(bS0 + 128, 65536 + 16384); GLDS(bS1 + 128, 65536 + 24576);
  VMW8(); BAR();

  // stage pointers for tile t+3
  const char* a0p = aS0 + 192;
  const char* a1p = aS1 + 192;
  const char* b0p = bS0 + 192;
  const char* b1p = bS1 + 192;

  for (int tt = 0; tt < 60; tt += 4) {  // tiles 0..59
    KT(0, 3, 0,   1, VMW8());
    KT(1, 0, 64,  1, VMW8());
    KT(2, 1, 128, 1, VMW8());
    KT(3, 2, 192, 1, VMW8());
    a0p += 256; a1p += 256; b0p += 256; b1p += 256;
  }
  // t=60 stages tile 63; tail drains
  KT(0, 3, 0, 1, VMW8());
  KT(1, 0, 0, 0, VMW4());
  KT(2, 0, 0, 0, VMW0());
  KT(3, 0, 0, 0, NOW());

  float* Pz = kz ? P1 : P0;
  const int r0 = brow + wm * 128 + (lane >> 4) * 4;
  const int c0 = bcol + wn * 64 + (lane & 15);
#pragma unroll
  for (int m = 0; m < 8; ++m)
#pragma unroll
    for (int n = 0; n < 4; ++n)
#pragma unroll
      for (int j = 0; j < 4; ++j)
        Pz[(size_t)(r0 + m * 16 + j) * OUT_DIM + (c0 + n * 16)] = acc[m][n][j];

  // fused column stats: each lane sums its 32 elements per n-block, then
  // xor-reduce over lanes ^16/^32 (4 lanes share a col), atomics from lane<16.
  float ps[4], pq[4];
#pragma unroll
  for (int n = 0; n < 4; ++n) {
    float s = 0.f, q = 0.f;
#pragma unroll
    for (int m = 0; m < 8; ++m)
#pragma unroll
      for (int j = 0; j < 4; ++j) {
        float v = acc[m][n][j];
        s += v; q += v * v;
      }
    s += __shfl_xor(s, 16); q += __shfl_xor(q, 16);
    s += __shfl_xor(s, 32); q += __shfl_xor(q, 32);
    ps[n] = s; pq[n] = q;
  }
  if (lane < 16) {
#pragma unroll
    for (int n = 0; n < 4; ++n) {
      atomicAdd(&sums[bcol + wn * 64 + n * 16 + lane], ps[n]);
      atomicAdd(&sqs[bcol + wn * 64 + n * 16 + lane], pq[n]);
    }
  }
}

// K3: fused partial-add + batchnorm, Y (=P0=d_out) in-place
__global__ void bnorm2(const float* __restrict__ P1, float* __restrict__ Y,
                       const float* __restrict__ sums, const float* __restrict__ sqs,
                       const float* __restrict__ gamma, const float* __restrict__ beta) {
  int e = (blockIdx.x * 256 + threadIdx.x) * 4;
  int c = e % OUT_DIM;
  float4 y = *(float4*)(Y + e);
  float4 p = *(const float4*)(P1 + e);
  y.x += p.x; y.y += p.y; y.z += p.z; y.w += p.w;
  float4 s = *(const float4*)(sums + c);
  float4 q = *(const float4*)(sqs + c);
  float4 g = *(const float4*)(gamma + c);
  float4 bb = *(const float4*)(beta + c);
  const float invB = 1.0f / (float)BATCH;
  float m0 = s.x * invB, m1 = s.y * invB, m2 = s.z * invB, m3 = s.w * invB;
  float i0 = rsqrtf(q.x * invB - m0 * m0 + BN_EPS);
  float i1 = rsqrtf(q.y * invB - m1 * m1 + BN_EPS);
  float i2 = rsqrtf(q.z * invB - m2 * m2 + BN_EPS);
  float i3 = rsqrtf(q.w * invB - m3 * m3 + BN_EPS);
  y.x = g.x * (y.x - m0) * i0 + bb.x;
  y.y = g.y * (y.y - m1) * i1 + bb.y;
  y.z = g.z * (y.z - m2) * i2 + bb.z;
  y.w = g.w * (y.w - m3) * i3 + bb.w;
  *(float4*)(Y + e) = y;
}

extern "C" void kernel_launch(void* const* d_in, const int* in_sizes, int n_in,
                              void* d_out, int out_size, void* d_ws, size_t ws_size,
                              hipStream_t stream) {
  const float* x         = (const float*)d_in[0];
  const float* scale     = (const float*)d_in[1];
  const float* translate = (const float*)d_in[2];
  const float* ww        = (const float*)d_in[3];
  const float* bw        = (const float*)d_in[4];
  const float* gamma     = (const float*)d_in[5];
  const float* beta      = (const float*)d_in[6];
  float* out = (float*)d_out;

  char* ws = (char*)d_ws;
  unsigned short* A = (unsigned short*)ws;                 // 33,554,432 B
  unsigned short* W = (unsigned short*)(ws + 33554432);    // 16,777,216 B
  float* P1   = (float*)(ws + 50331648);                   // 33,554,432 B
  float* sums = (float*)(ws + 83886080);
  float* sqs  = sums + OUT_DIM;

  hipMemsetAsync(sums, 0, 2 * OUT_DIM * sizeof(float), stream);
  prep_act<<<(BATCH * IN_DIM) / 1024, 256, 0, stream>>>(x, scale, translate, A);
  prep_w<<<(OUT_DIM * IN_DIM) / 1024, 256, 0, stream>>>(ww, bw, W);
  gemm256<<<256, 512, 0, stream>>>(A, W, out, P1, sums, sqs);
  bnorm2<<<(BATCH * OUT_DIM) / 1024, 256, 0, stream>>>(P1, out, sums, sqs, gamma, beta);
}